// Round 1
// baseline (3505.628 us; speedup 1.0000x reference)
//
#include <hip/hip_runtime.h>
#include <hip/hip_bf16.h>
#include <math.h>

#define Bn   4
#define CINn 16
#define HIDn 16
#define Tn   31
#define Hn   128
#define Wn   128
#define OCn  64
#define TAPSn 27

// Repack W[oc][cin][kd][kh][kw] (oc-major) -> Wr[tap][cin][oc] (oc contiguous)
// so the main kernel's weight reads are wave-uniform and oc-contiguous.
__global__ void repack_w_kernel(const float* __restrict__ W, float* __restrict__ Wr) {
    int idx = blockIdx.x * blockDim.x + threadIdx.x;
    if (idx >= OCn * CINn * TAPSn) return;
    int oc  = idx / (CINn * TAPSn);
    int rem = idx - oc * (CINn * TAPSn);
    int cin = rem / TAPSn;
    int tap = rem - cin * TAPSn;
    Wr[(tap * CINn + cin) * OCn + oc] = W[idx];
}

__device__ __forceinline__ float sigmoidf_(float x) { return 1.f / (1.f + __expf(-x)); }
__device__ __forceinline__ float tanhf_(float x)    { return 2.f / (1.f + __expf(-2.f * x)) - 1.f; }

// One workgroup per (b, h). 128 threads = one per w. Thread keeps c[16] in
// registers across the T loop (recurrence fused). Rolling 3-slice bf16 LDS
// ring for X (time t-1, t, t+1), one new slice staged per t.
__global__ __launch_bounds__(128, 1)
void qrnn_fused_kernel(const float* __restrict__ X, const float* __restrict__ Wr,
                       const float* __restrict__ bias, float* __restrict__ out) {
    extern __shared__ __hip_bfloat16 smem[];  // [3 slots][3 rows][16 cin][132 w]
    const int tid = threadIdx.x;              // w coordinate, 0..127
    const int b   = blockIdx.x >> 7;
    const int h   = blockIdx.x & 127;

    const size_t strideT = (size_t)Hn * Wn;        // 16384
    const size_t strideC = (size_t)Tn * strideT;   // 507904
    const float* Xb = X + (size_t)b * CINn * strideC;

    auto XS = [&](int slot, int r, int cin, int wi) -> __hip_bfloat16& {
        return smem[(((slot * 3 + r) * CINn + cin) * 132) + wi];
    };

    // Stage time slice u (rows h-1..h+1, all cin, w with halo) into ring slot s.
    auto stage = [&](int u, int s) {
        for (int idx = tid; idx < 3 * CINn * 130; idx += 128) {
            int wi  = idx % 130;          // 0..129  -> w = wi-1 in -1..128
            int rc  = idx / 130;          // 0..47
            int cin = rc & 15;
            int r   = rc >> 4;            // 0..2 -> row h-1+r
            int hr  = h - 1 + r;
            float v = 0.f;
            if (u >= 0 && u < Tn && hr >= 0 && hr < Hn && wi >= 1 && wi <= 128)
                v = Xb[(size_t)cin * strideC + (size_t)u * strideT + (size_t)hr * Wn + (wi - 1)];
            XS(s, r, cin, wi) = __float2bfloat16(v);
        }
    };

    float c[HIDn];
    #pragma unroll
    for (int i = 0; i < HIDn; i++) c[i] = 0.f;

    // slot(u) = ((u % 3) + 3) % 3 ; pre-stage u=-1 (zeros) and u=0.
    stage(-1, 2);
    stage(0, 0);

    float* outb = out + (size_t)b * HIDn * strideC + (size_t)h * Wn + tid;

    for (int t = 0; t < Tn; t++) {
        stage(t + 1, (t + 1) % 3);   // u=31 stages zeros
        __syncthreads();

        float g[OCn];
        #pragma unroll
        for (int i = 0; i < OCn; i++) g[i] = 0.f;

        const int s0 = (t + 2) % 3;  // slot(t-1)
        const int s1 = t % 3;        // slot(t)
        const int s2 = (t + 1) % 3;  // slot(t+1)

        #pragma unroll
        for (int kd = 0; kd < 3; kd++) {
            const int sl = (kd == 0) ? s0 : (kd == 1) ? s1 : s2;
            #pragma unroll
            for (int kh = 0; kh < 3; kh++) {
                #pragma unroll
                for (int kw = 0; kw < 3; kw++) {
                    const float* __restrict__ wtap =
                        Wr + (size_t)((kd * 9 + kh * 3 + kw) * CINn) * OCn;
                    for (int cin = 0; cin < CINn; cin++) {
                        // X[t-1+kd][h-1+kh][w-1+kw] ; wi = tid + kw
                        float xv = __bfloat162float(XS(sl, kh, cin, tid + kw));
                        const float* __restrict__ wrow = wtap + cin * OCn; // wave-uniform -> s_load
                        #pragma unroll
                        for (int oc = 0; oc < OCn; oc++)
                            g[oc] = fmaf(wrow[oc], xv, g[oc]);
                    }
                }
            }
        }

        // activations + recurrence + store
        #pragma unroll
        for (int hd = 0; hd < HIDn; hd++) {
            float z = tanhf_   (g[hd]            + bias[hd]);
            float f = sigmoidf_(g[HIDn + hd]     + bias[HIDn + hd]);
            float o = sigmoidf_(g[2 * HIDn + hd] + bias[2 * HIDn + hd]);
            float i = sigmoidf_(g[3 * HIDn + hd] + bias[3 * HIDn + hd]);
            c[hd] = f * c[hd] + i * z;
            outb[(size_t)hd * strideC + (size_t)t * strideT] = o * c[hd];
        }
        __syncthreads();  // protect ring slot reused by next t's stage
    }
}

extern "C" void kernel_launch(void* const* d_in, const int* in_sizes, int n_in,
                              void* d_out, int out_size, void* d_ws, size_t ws_size,
                              hipStream_t stream) {
    const float* X    = (const float*)d_in[0];
    const float* W    = (const float*)d_in[1];
    const float* bias = (const float*)d_in[2];
    float* out = (float*)d_out;
    float* Wr  = (float*)d_ws;   // 27648 floats = 110592 B

    repack_w_kernel<<<(OCn * CINn * TAPSn + 255) / 256, 256, 0, stream>>>(W, Wr);

    const int lds_bytes = 3 * 3 * CINn * 132 * (int)sizeof(__hip_bfloat16); // 38016
    qrnn_fused_kernel<<<Bn * Hn, 128, lds_bytes, stream>>>(X, Wr, bias, out);
}